// Round 1
// baseline (391.531 us; speedup 1.0000x reference)
//
#include <hip/hip_runtime.h>
#include <hip/hip_bf16.h>

typedef unsigned short ushort_t;
typedef unsigned int uint_t;

__device__ __forceinline__ float bf2f(ushort_t u) {
    union { uint_t u; float f; } v; v.u = (uint_t)u << 16; return v.f;
}
__device__ __forceinline__ ushort_t f2bf(float f) {
    union { float f; uint_t u; } v; v.f = f;
    uint_t u = v.u;
    return (ushort_t)((u + 0x7fffu + ((u >> 16) & 1u)) >> 16);  // round-nearest-even
}

// -------- Kernel 1: pointwise conv (w_in,b_in) + BN folded, fp32 in -> bf16 channel-last out
// x: (4,64,256,256) f32.  xbn: (4,256,256,64) bf16.
__global__ __launch_bounds__(256) void k1_pwbn(
    const float* __restrict__ x, const float* __restrict__ w_in, const float* __restrict__ b_in,
    const float* __restrict__ gamma, const float* __restrict__ beta,
    const float* __restrict__ mean, const float* __restrict__ var,
    ushort_t* __restrict__ xbn)
{
    __shared__ float wef[64][64];
    __shared__ float bef[64];
    int tid = threadIdx.x;
    for (int idx = tid; idx < 4096; idx += 256) {
        int o = idx >> 6;
        wef[o][idx & 63] = w_in[idx] * (gamma[o] * rsqrtf(var[o] + 1e-5f));
    }
    if (tid < 64) {
        float inv = gamma[tid] * rsqrtf(var[tid] + 1e-5f);
        bef[tid] = (b_in[tid] - mean[tid]) * inv + beta[tid];
    }
    __syncthreads();

    int b  = blockIdx.x >> 8;                 // 256 tiles per batch
    int hw = ((blockIdx.x & 255) << 8) | tid; // pixel index within batch
    const float* xb = x + ((size_t)b << 22) + hw;

    float xr[64];
    #pragma unroll
    for (int c = 0; c < 64; ++c) xr[c] = xb[(size_t)c << 16];

    ushort_t* op = xbn + ((((size_t)b << 16) | (size_t)hw) << 6);
    for (int og = 0; og < 8; ++og) {
        union { int4 v; ushort_t s[8]; } pk;
        #pragma unroll
        for (int oi = 0; oi < 8; ++oi) {
            int o = og * 8 + oi;
            float acc = bef[o];
            #pragma unroll
            for (int c = 0; c < 64; ++c) acc += xr[c] * wef[o][c];
            pk.s[oi] = f2bf(acc);
        }
        *(int4*)(op + og * 8) = pk.v;
    }
}

// -------- Kernel 2: per-window attention + output projection
// One block per window. b=4, hh=ww=32 -> 4096 blocks, 256 threads.
__global__ __launch_bounds__(256, 2) void k2_attn(
    const ushort_t* __restrict__ xbn,
    const float* __restrict__ w_mask, const float* __restrict__ b_mask,
    const float* __restrict__ w_out,  const float* __restrict__ b_out,
    float* __restrict__ out)
{
    __shared__ float A[64][65];   // g (q-input), then scores S (exp'ed)
    __shared__ float Q[64][65];   // q, then Y
    __shared__ float V[64][65];   // v, then Out^T (o-major) for coalesced store
    __shared__ float W[64][65];   // w_mask, then w_out
    __shared__ float red[64][4];
    __shared__ float red2[64][4];
    __shared__ float rs[64];

    int tid = threadIdx.x;
    int wid = blockIdx.x;
    int b = wid >> 10;
    int i = (wid >> 5) & 31;
    int j = wid & 31;

    const ushort_t* xb = xbn + ((size_t)b << 22);  // b * 65536 pixels * 64 ch

    // stage w_mask
    for (int idx = tid; idx < 4096; idx += 256)
        W[idx >> 6][idx & 63] = w_mask[idx];

    // stage g: q-token t -> r = t&7 (row offset idx), s = t>>3 (col offset idx)
    {
        int t = tid >> 2, seg = tid & 3;
        int r = t & 7, s = t >> 3;
        int pr = i * 8 + 2 * r; if (pr >= 256) pr -= 8;   // wrap-pad
        int pc = j * 8 + 2 * s; if (pc >= 256) pc -= 8;
        const ushort_t* src = xb + (((size_t)((pr << 8) | pc)) << 6) + seg * 16;
        int4 u0 = *(const int4*)src;
        int4 u1 = *(const int4*)(src + 8);
        const ushort_t* p0 = (const ushort_t*)&u0;
        const ushort_t* p1 = (const ushort_t*)&u1;
        #pragma unroll
        for (int k = 0; k < 8; ++k) A[t][seg * 16 + k]     = bf2f(p0[k]);
        #pragma unroll
        for (int k = 0; k < 8; ++k) A[t][seg * 16 + 8 + k] = bf2f(p1[k]);
    }
    // stage v: v-token t -> row = i*8 + (t>>3), col = j*8 + (t&7)  (row-major)
    {
        int t = tid >> 2, seg = tid & 3;
        int pr = i * 8 + (t >> 3);
        int pc = j * 8 + (t & 7);
        const ushort_t* src = xb + (((size_t)((pr << 8) | pc)) << 6) + seg * 16;
        int4 u0 = *(const int4*)src;
        int4 u1 = *(const int4*)(src + 8);
        const ushort_t* p0 = (const ushort_t*)&u0;
        const ushort_t* p1 = (const ushort_t*)&u1;
        #pragma unroll
        for (int k = 0; k < 8; ++k) V[t][seg * 16 + k]     = bf2f(p0[k]);
        #pragma unroll
        for (int k = 0; k < 8; ++k) V[t][seg * 16 + 8 + k] = bf2f(p1[k]);
    }
    __syncthreads();

    int tr = tid >> 4, tc = tid & 15;
    float acc[4][4];

    // M1: Q = g @ w_mask^T + b_mask   (rows = tokens, cols = o)
    {
        float bm[4];
        #pragma unroll
        for (int jj = 0; jj < 4; ++jj) bm[jj] = b_mask[tc * 4 + jj];
        #pragma unroll
        for (int ii = 0; ii < 4; ++ii)
            #pragma unroll
            for (int jj = 0; jj < 4; ++jj) acc[ii][jj] = bm[jj];
        for (int c = 0; c < 64; ++c) {
            float av[4], bv[4];
            #pragma unroll
            for (int ii = 0; ii < 4; ++ii) av[ii] = A[tr * 4 + ii][c];
            #pragma unroll
            for (int jj = 0; jj < 4; ++jj) bv[jj] = W[tc * 4 + jj][c];
            #pragma unroll
            for (int ii = 0; ii < 4; ++ii)
                #pragma unroll
                for (int jj = 0; jj < 4; ++jj) acc[ii][jj] += av[ii] * bv[jj];
        }
    }
    #pragma unroll
    for (int ii = 0; ii < 4; ++ii)
        #pragma unroll
        for (int jj = 0; jj < 4; ++jj) Q[tr * 4 + ii][tc * 4 + jj] = acc[ii][jj];
    __syncthreads();

    // M2: S = Q @ Q^T  -> into A ; also stage w_out into W (its w_mask reads are done)
    {
        #pragma unroll
        for (int ii = 0; ii < 4; ++ii)
            #pragma unroll
            for (int jj = 0; jj < 4; ++jj) acc[ii][jj] = 0.f;
        for (int c = 0; c < 64; ++c) {
            float av[4], bv[4];
            #pragma unroll
            for (int ii = 0; ii < 4; ++ii) av[ii] = Q[tr * 4 + ii][c];
            #pragma unroll
            for (int jj = 0; jj < 4; ++jj) bv[jj] = Q[tc * 4 + jj][c];
            #pragma unroll
            for (int ii = 0; ii < 4; ++ii)
                #pragma unroll
                for (int jj = 0; jj < 4; ++jj) acc[ii][jj] += av[ii] * bv[jj];
        }
        for (int idx = tid; idx < 4096; idx += 256)
            W[idx >> 6][idx & 63] = w_out[idx];
        #pragma unroll
        for (int ii = 0; ii < 4; ++ii)
            #pragma unroll
            for (int jj = 0; jj < 4; ++jj) A[tr * 4 + ii][tc * 4 + jj] = acc[ii][jj];
    }
    __syncthreads();

    // softmax rows of A (leave unnormalized exp; rs[row] = 1/sum)
    {
        int row = tid >> 2, p = tid & 3;
        float m = -1e30f;
        #pragma unroll
        for (int k = 0; k < 16; ++k) m = fmaxf(m, A[row][p * 16 + k]);
        red[row][p] = m;
        __syncthreads();
        m = fmaxf(fmaxf(red[row][0], red[row][1]), fmaxf(red[row][2], red[row][3]));
        float ssum = 0.f;
        #pragma unroll
        for (int k = 0; k < 16; ++k) {
            float e = __expf(A[row][p * 16 + k] - m);
            A[row][p * 16 + k] = e;
            ssum += e;
        }
        red2[row][p] = ssum;
        __syncthreads();
        float tot = red2[row][0] + red2[row][1] + red2[row][2] + red2[row][3];
        if (p == 0) rs[row] = 1.0f / tot;
    }
    __syncthreads();

    // M3: Y = P @ V -> into Q (scaled by 1/rowsum)
    {
        #pragma unroll
        for (int ii = 0; ii < 4; ++ii)
            #pragma unroll
            for (int jj = 0; jj < 4; ++jj) acc[ii][jj] = 0.f;
        for (int k = 0; k < 64; ++k) {
            float av[4], bv[4];
            #pragma unroll
            for (int ii = 0; ii < 4; ++ii) av[ii] = A[tr * 4 + ii][k];
            #pragma unroll
            for (int jj = 0; jj < 4; ++jj) bv[jj] = V[k][tc * 4 + jj];
            #pragma unroll
            for (int ii = 0; ii < 4; ++ii)
                #pragma unroll
                for (int jj = 0; jj < 4; ++jj) acc[ii][jj] += av[ii] * bv[jj];
        }
    }
    __syncthreads();   // all V reads done before Y write? (V reads are above; barrier also orders Q reuse)
    #pragma unroll
    for (int ii = 0; ii < 4; ++ii)
        #pragma unroll
        for (int jj = 0; jj < 4; ++jj)
            Q[tr * 4 + ii][tc * 4 + jj] = acc[ii][jj] * rs[tr * 4 + ii];
    __syncthreads();

    // M4: Out = Y @ w_out^T + b_out -> write transposed into V[o][t]
    {
        float bo[4];
        #pragma unroll
        for (int jj = 0; jj < 4; ++jj) bo[jj] = b_out[tc * 4 + jj];
        #pragma unroll
        for (int ii = 0; ii < 4; ++ii)
            #pragma unroll
            for (int jj = 0; jj < 4; ++jj) acc[ii][jj] = bo[jj];
        for (int c = 0; c < 64; ++c) {
            float av[4], bv[4];
            #pragma unroll
            for (int ii = 0; ii < 4; ++ii) av[ii] = Q[tr * 4 + ii][c];
            #pragma unroll
            for (int jj = 0; jj < 4; ++jj) bv[jj] = W[tc * 4 + jj][c];
            #pragma unroll
            for (int ii = 0; ii < 4; ++ii)
                #pragma unroll
                for (int jj = 0; jj < 4; ++jj) acc[ii][jj] += av[ii] * bv[jj];
        }
        #pragma unroll
        for (int ii = 0; ii < 4; ++ii)
            #pragma unroll
            for (int jj = 0; jj < 4; ++jj)
                V[tc * 4 + jj][tr * 4 + ii] = acc[ii][jj];   // V[o][t]
    }
    __syncthreads();

    // coalesced global store: y token t is row-major (row = t>>3, col = t&7)
    {
        float* ob = out + ((size_t)b << 22);
        int base = (i * 8) * 256 + j * 8;
        for (int p = 0; p < 16; ++p) {
            int e = p * 256 + tid;
            int o = e >> 6, t = e & 63;
            ob[((size_t)o << 16) + base + ((t >> 3) << 8) + (t & 7)] = V[o][t];
        }
    }
}

extern "C" void kernel_launch(void* const* d_in, const int* in_sizes, int n_in,
                              void* d_out, int out_size, void* d_ws, size_t ws_size,
                              hipStream_t stream) {
    const float* x      = (const float*)d_in[0];
    const float* w_in   = (const float*)d_in[1];
    const float* b_in   = (const float*)d_in[2];
    const float* gamma  = (const float*)d_in[3];
    const float* beta   = (const float*)d_in[4];
    const float* mean   = (const float*)d_in[5];
    const float* var    = (const float*)d_in[6];
    const float* w_mask = (const float*)d_in[7];
    const float* b_mask = (const float*)d_in[8];
    const float* w_out  = (const float*)d_in[9];
    const float* b_out  = (const float*)d_in[10];
    float* out = (float*)d_out;
    ushort_t* xbn = (ushort_t*)d_ws;   // 4*256*256*64 bf16 = 33.5 MB

    hipLaunchKernelGGL(k1_pwbn, dim3(1024), dim3(256), 0, stream,
                       x, w_in, b_in, gamma, beta, mean, var, xbn);
    hipLaunchKernelGGL(k2_attn, dim3(4096), dim3(256), 0, stream,
                       xbn, w_mask, b_mask, w_out, b_out, out);
}

// Round 4
// 283.434 us; speedup vs baseline: 1.3814x; 1.3814x over previous
//
#include <hip/hip_runtime.h>

typedef unsigned short ushort_t;
typedef unsigned int uint_t;

__device__ __forceinline__ float bf2f(ushort_t u) {
    union { uint_t u; float f; } v; v.u = (uint_t)u << 16; return v.f;
}
__device__ __forceinline__ ushort_t f2bf(float f) {
    union { float f; uint_t u; } v; v.f = f;
    uint_t u = v.u;
    return (ushort_t)((u + 0x7fffu + ((u >> 16) & 1u)) >> 16);  // RNE
}

// ---------------- Kernel 1: pointwise conv + BN fold, LDS-tiled GEMM ----------------
// x: (4,64,256,256) f32 -> xbn: (4*65536, 64) bf16 (channel-last).
// Block: 128 pixels x 64 outs. x is [c][hw]-major == K-major already (no transpose needed).
__global__ __launch_bounds__(256) void k1_pwbn(
    const float* __restrict__ x, const float* __restrict__ w_in, const float* __restrict__ b_in,
    const float* __restrict__ gamma, const float* __restrict__ beta,
    const float* __restrict__ mean, const float* __restrict__ var,
    ushort_t* __restrict__ xbn)
{
    __shared__ float Xt[64][132];   // [c][pix], 33.0 KB (pad to 132 keeps 16B row align)
    __shared__ float WT[64][68];    // wefT[c][o], 17.4 KB
    __shared__ float bef[64];

    int tid = threadIdx.x;
    int b   = blockIdx.x >> 9;            // 512 blocks of 128 px per batch image
    int hw0 = (blockIdx.x & 511) << 7;
    const float* xb = x + ((size_t)b << 22);

    // stage wefT = (w_in * gamma/sqrt(var+eps)) transposed (one-time; conflicts OK)
    for (int e = 0; e < 16; ++e) {
        int idx = e * 256 + tid;
        int o = idx >> 6, c = idx & 63;
        WT[c][o] = w_in[idx] * gamma[o] * rsqrtf(var[o] + 1e-5f);
    }
    if (tid < 64) {
        float inv = gamma[tid] * rsqrtf(var[tid] + 1e-5f);
        bef[tid] = (b_in[tid] - mean[tid]) * inv + beta[tid];
    }
    // stage Xt: contiguous float4 copy (x plane-major == exactly Xt layout)
    for (int e = 0; e < 8; ++e) {
        int i16 = e * 256 + tid;          // 2048 16B chunks = 64c x 32chunks
        int c = i16 >> 5, s = i16 & 31;
        *(float4*)&Xt[c][s * 4] = *(const float4*)(xb + ((size_t)c << 16) + hw0 + s * 4);
    }
    __syncthreads();

    // GEMM: thread (tr=tid>>3 -> 4 pixels, tc=tid&7 -> 8 outs)
    int tr = tid >> 3, tc = tid & 7;
    float acc[4][8];
    #pragma unroll
    for (int p = 0; p < 4; ++p)
        #pragma unroll
        for (int q = 0; q < 8; ++q) acc[p][q] = 0.f;

    for (int c = 0; c < 64; ++c) {
        float4 a4 = *(const float4*)&Xt[c][4 * tr];
        float4 b0 = *(const float4*)&WT[c][8 * tc];
        float4 b1 = *(const float4*)&WT[c][8 * tc + 4];
        float av[4] = {a4.x, a4.y, a4.z, a4.w};
        float bv[8] = {b0.x, b0.y, b0.z, b0.w, b1.x, b1.y, b1.z, b1.w};
        #pragma unroll
        for (int p = 0; p < 4; ++p)
            #pragma unroll
            for (int q = 0; q < 8; ++q) acc[p][q] += av[p] * bv[q];
    }

    // epilogue: +bias, bf16 pack, 16B stores (wave writes 1KB contiguous)
    float bo[8];
    #pragma unroll
    for (int q = 0; q < 8; ++q) bo[q] = bef[8 * tc + q];
    ushort_t* xp = xbn + ((size_t)(b * 65536 + hw0 + 4 * tr) << 6) + 8 * tc;
    #pragma unroll
    for (int p = 0; p < 4; ++p) {
        union { int4 v; ushort_t s[8]; } pk;
        #pragma unroll
        for (int q = 0; q < 8; ++q) pk.s[q] = f2bf(acc[p][q] + bo[q]);
        *(int4*)(xp + (size_t)p * 64) = pk.v;
    }
}

// ---------------- Kernel 2: per-window attention + out-proj, K-major LDS ----------------
// All GEMMs read A'[k][m], B'[k][n] as float4 along m/n -> 2 ds_read_b128 per k per thread.
__global__ __launch_bounds__(256, 2) void k2_attn(
    const ushort_t* __restrict__ xbn,
    const float* __restrict__ w_mask, const float* __restrict__ b_mask,
    const float* __restrict__ w_out,  const float* __restrict__ b_out,
    float* __restrict__ out)
{
    __shared__ float B1[64][68];   // gT[c][t] -> S/P[u][t] -> OutT[o][t]
    __shared__ float B2[64][68];   // qT[o][t] -> YT[c][t]
    __shared__ float B3[64][68];   // V[u][c]  (already K-major for M3 B-operand)
    __shared__ float B4[64][68];   // wmT[c][o] -> woT[c][o]
    __shared__ float mbuf[64];
    __shared__ float red[64][4];
    __shared__ float rsinv[64];

    int tid = threadIdx.x;
    int wid = blockIdx.x;
    int b = wid >> 10, i = (wid >> 5) & 31, j = wid & 31;
    const ushort_t* xb = xbn + ((size_t)b << 22);

    // stage wmT (coalesced global read, transposed LDS write; one-time)
    for (int e = 0; e < 16; ++e) {
        int idx = e * 256 + tid;
        B4[idx & 63][idx >> 6] = w_mask[idx];
    }
    // stage gT[c][t]: q-token t: r=t&7 (row), s=t>>3 (col), stride-2 + wrap pad
    {
        int t = tid >> 2, seg = tid & 3;
        int r = t & 7, s = t >> 3;
        int pr = i * 8 + 2 * r; if (pr >= 256) pr -= 8;
        int pc = j * 8 + 2 * s; if (pc >= 256) pc -= 8;
        const ushort_t* src = xb + (((size_t)((pr << 8) | pc)) << 6) + seg * 16;
        union { int4 v[2]; ushort_t s[16]; } u;
        u.v[0] = *(const int4*)src;
        u.v[1] = *(const int4*)(src + 8);
        #pragma unroll
        for (int k = 0; k < 16; ++k) {           // seg-staggered order: 2-way banks
            int kk = (k + 4 * seg) & 15;
            B1[seg * 16 + kk][t] = bf2f(u.s[kk]);
        }
    }
    // stage V[u][c]: v-token u row-major in window; vectorized b128 writes
    {
        int t = tid >> 2, seg = tid & 3;
        int pr = i * 8 + (t >> 3), pc = j * 8 + (t & 7);
        const ushort_t* src = xb + (((size_t)((pr << 8) | pc)) << 6) + seg * 16;
        union { int4 v[2]; ushort_t s[16]; } u;
        u.v[0] = *(const int4*)src;
        u.v[1] = *(const int4*)(src + 8);
        #pragma unroll
        for (int q = 0; q < 4; ++q) {
            float4 f;
            f.x = bf2f(u.s[4 * q + 0]); f.y = bf2f(u.s[4 * q + 1]);
            f.z = bf2f(u.s[4 * q + 2]); f.w = bf2f(u.s[4 * q + 3]);
            *(float4*)&B3[t][seg * 16 + 4 * q] = f;
        }
    }
    __syncthreads();

    int tr = tid >> 4, tc = tid & 15;
    float acc[4][4];

    // M1: q[t][o] = sum_c gT[c][t] * wmT[c][o] + b_mask[o]  -> write qT[o][t]
    {
        float4 bm = *(const float4*)&b_mask[4 * tc];
        float bmv[4] = {bm.x, bm.y, bm.z, bm.w};
        #pragma unroll
        for (int ii = 0; ii < 4; ++ii)
            #pragma unroll
            for (int jj = 0; jj < 4; ++jj) acc[ii][jj] = bmv[jj];
        for (int k = 0; k < 64; ++k) {
            float4 a4 = *(const float4*)&B1[k][4 * tr];
            float4 b4 = *(const float4*)&B4[k][4 * tc];
            float av[4] = {a4.x, a4.y, a4.z, a4.w};
            float bv[4] = {b4.x, b4.y, b4.z, b4.w};
            #pragma unroll
            for (int ii = 0; ii < 4; ++ii)
                #pragma unroll
                for (int jj = 0; jj < 4; ++jj) acc[ii][jj] += av[ii] * bv[jj];
        }
        #pragma unroll
        for (int jj = 0; jj < 4; ++jj) {
            float4 w = make_float4(acc[0][jj], acc[1][jj], acc[2][jj], acc[3][jj]);
            *(float4*)&B2[4 * tc + jj][4 * tr] = w;
        }
    }
    __syncthreads();

    // stage woT into B4 (wmT dead after M1)
    for (int e = 0; e < 16; ++e) {
        int idx = e * 256 + tid;
        B4[idx & 63][idx >> 6] = w_out[idx];
    }

    // M2: S[t][u] = sum_o qT[o][t] qT[o][u]  (symmetric) -> write row-major into B1
    {
        #pragma unroll
        for (int ii = 0; ii < 4; ++ii)
            #pragma unroll
            for (int jj = 0; jj < 4; ++jj) acc[ii][jj] = 0.f;
        for (int k = 0; k < 64; ++k) {
            float4 a4 = *(const float4*)&B2[k][4 * tr];
            float4 b4 = *(const float4*)&B2[k][4 * tc];
            float av[4] = {a4.x, a4.y, a4.z, a4.w};
            float bv[4] = {b4.x, b4.y, b4.z, b4.w};
            #pragma unroll
            for (int ii = 0; ii < 4; ++ii)
                #pragma unroll
                for (int jj = 0; jj < 4; ++jj) acc[ii][jj] += av[ii] * bv[jj];
        }
        #pragma unroll
        for (int ii = 0; ii < 4; ++ii)
            *(float4*)&B1[4 * tr + ii][4 * tc] =
                make_float4(acc[ii][0], acc[ii][1], acc[ii][2], acc[ii][3]);
    }
    __syncthreads();

    // softmax pass1: row maxes (rows of S == cols by symmetry)
    {
        int a = tid >> 2, p = tid & 3;
        float m = -1e30f;
        #pragma unroll
        for (int q = 0; q < 4; ++q) {
            float4 s4 = *(const float4*)&B1[a][16 * p + 4 * q];
            m = fmaxf(m, fmaxf(fmaxf(s4.x, s4.y), fmaxf(s4.z, s4.w)));
        }
        red[a][p] = m;
    }
    __syncthreads();
    if (tid < 64)
        mbuf[tid] = fmaxf(fmaxf(red[tid][0], red[tid][1]), fmaxf(red[tid][2], red[tid][3]));
    __syncthreads();
    // pass2: P[a][b] = exp(S[a][b] - m[b])   (so P[u][t] = exp(S[t][u]-m[t]) by symmetry)
    {
        int a = tid >> 2, p = tid & 3;
        #pragma unroll
        for (int q = 0; q < 4; ++q) {
            float4 s4 = *(const float4*)&B1[a][16 * p + 4 * q];
            float4 m4 = *(const float4*)&mbuf[16 * p + 4 * q];
            s4.x = __expf(s4.x - m4.x); s4.y = __expf(s4.y - m4.y);
            s4.z = __expf(s4.z - m4.z); s4.w = __expf(s4.w - m4.w);
            *(float4*)&B1[a][16 * p + 4 * q] = s4;
        }
    }
    __syncthreads();
    // pass3: rs[t] = sum_a P[a][t] (column sums; staggered for banks)
    {
        int t = tid >> 2, p = tid & 3;
        float ssum = 0.f;
        #pragma unroll
        for (int k = 0; k < 16; ++k) {
            int kk = (k + 4 * p) & 15;
            ssum += B1[16 * p + kk][t];
        }
        red[t][p] = ssum;
    }
    __syncthreads();
    if (tid < 64)
        rsinv[tid] = 1.0f / (red[tid][0] + red[tid][1] + red[tid][2] + red[tid][3]);
    __syncthreads();

    // M3: Y[t][c] = (sum_u P[u][t] V[u][c]) * rsinv[t] -> write YT[c][t]
    {
        #pragma unroll
        for (int ii = 0; ii < 4; ++ii)
            #pragma unroll
            for (int jj = 0; jj < 4; ++jj) acc[ii][jj] = 0.f;
        for (int k = 0; k < 64; ++k) {
            float4 a4 = *(const float4*)&B1[k][4 * tr];
            float4 b4 = *(const float4*)&B3[k][4 * tc];
            float av[4] = {a4.x, a4.y, a4.z, a4.w};
            float bv[4] = {b4.x, b4.y, b4.z, b4.w};
            #pragma unroll
            for (int ii = 0; ii < 4; ++ii)
                #pragma unroll
                for (int jj = 0; jj < 4; ++jj) acc[ii][jj] += av[ii] * bv[jj];
        }
        float4 rv = *(const float4*)&rsinv[4 * tr];
        float rvv[4] = {rv.x, rv.y, rv.z, rv.w};
        #pragma unroll
        for (int jj = 0; jj < 4; ++jj) {
            float4 w = make_float4(acc[0][jj] * rvv[0], acc[1][jj] * rvv[1],
                                   acc[2][jj] * rvv[2], acc[3][jj] * rvv[3]);
            *(float4*)&B2[4 * tc + jj][4 * tr] = w;
        }
    }
    __syncthreads();

    // M4: out[t][o] = sum_c YT[c][t] woT[c][o] + b_out[o] -> write OutT[o][t] into B1
    {
        float4 bo = *(const float4*)&b_out[4 * tc];
        float bov[4] = {bo.x, bo.y, bo.z, bo.w};
        #pragma unroll
        for (int ii = 0; ii < 4; ++ii)
            #pragma unroll
            for (int jj = 0; jj < 4; ++jj) acc[ii][jj] = bov[jj];
        for (int k = 0; k < 64; ++k) {
            float4 a4 = *(const float4*)&B2[k][4 * tr];
            float4 b4 = *(const float4*)&B4[k][4 * tc];
            float av[4] = {a4.x, a4.y, a4.z, a4.w};
            float bv[4] = {b4.x, b4.y, b4.z, b4.w};
            #pragma unroll
            for (int ii = 0; ii < 4; ++ii)
                #pragma unroll
                for (int jj = 0; jj < 4; ++jj) acc[ii][jj] += av[ii] * bv[jj];
        }
        #pragma unroll
        for (int jj = 0; jj < 4; ++jj) {
            float4 w = make_float4(acc[0][jj], acc[1][jj], acc[2][jj], acc[3][jj]);
            *(float4*)&B1[4 * tc + jj][4 * tr] = w;
        }
    }
    __syncthreads();

    // coalesced global store from OutT
    {
        float* ob = out + ((size_t)b << 22);
        int base = (i * 8) * 256 + j * 8;
        for (int p = 0; p < 16; ++p) {
            int e = p * 256 + tid;
            int o = e >> 6, t = e & 63;
            ob[((size_t)o << 16) + base + ((t >> 3) << 8) + (t & 7)] = B1[o][t];
        }
    }
}

extern "C" void kernel_launch(void* const* d_in, const int* in_sizes, int n_in,
                              void* d_out, int out_size, void* d_ws, size_t ws_size,
                              hipStream_t stream) {
    const float* x      = (const float*)d_in[0];
    const float* w_in   = (const float*)d_in[1];
    const float* b_in   = (const float*)d_in[2];
    const float* gamma  = (const float*)d_in[3];
    const float* beta   = (const float*)d_in[4];
    const float* mean   = (const float*)d_in[5];
    const float* var    = (const float*)d_in[6];
    const float* w_mask = (const float*)d_in[7];
    const float* b_mask = (const float*)d_in[8];
    const float* w_out  = (const float*)d_in[9];
    const float* b_out  = (const float*)d_in[10];
    float* out = (float*)d_out;
    ushort_t* xbn = (ushort_t*)d_ws;   // 4*65536*64 bf16 = 33.5 MB

    hipLaunchKernelGGL(k1_pwbn, dim3(2048), dim3(256), 0, stream,
                       x, w_in, b_in, gamma, beta, mean, var, xbn);
    hipLaunchKernelGGL(k2_attn, dim3(4096), dim3(256), 0, stream,
                       xbn, w_mask, b_mask, w_out, b_out, out);
}

// Round 5
// 201.474 us; speedup vs baseline: 1.9433x; 1.4068x over previous
//
#include <hip/hip_runtime.h>

typedef unsigned short ushort_t;
typedef unsigned int uint_t;
typedef __attribute__((ext_vector_type(8))) short short8v;
typedef __attribute__((ext_vector_type(4))) float f32x4;

__device__ __forceinline__ float bf2f(ushort_t u) {
    union { uint_t u; float f; } v; v.u = (uint_t)u << 16; return v.f;
}
__device__ __forceinline__ ushort_t f2bf(float f) {
    union { float f; uint_t u; } v; v.f = f;
    uint_t u = v.u;
    return (ushort_t)((u + 0x7fffu + ((u >> 16) & 1u)) >> 16);  // RNE
}

// ---------------- Kernel 1: pointwise conv + BN fold, LDS-tiled GEMM (UNCHANGED) ----
__global__ __launch_bounds__(256) void k1_pwbn(
    const float* __restrict__ x, const float* __restrict__ w_in, const float* __restrict__ b_in,
    const float* __restrict__ gamma, const float* __restrict__ beta,
    const float* __restrict__ mean, const float* __restrict__ var,
    ushort_t* __restrict__ xbn)
{
    __shared__ float Xt[64][132];
    __shared__ float WT[64][68];
    __shared__ float bef[64];

    int tid = threadIdx.x;
    int b   = blockIdx.x >> 9;
    int hw0 = (blockIdx.x & 511) << 7;
    const float* xb = x + ((size_t)b << 22);

    for (int e = 0; e < 16; ++e) {
        int idx = e * 256 + tid;
        int o = idx >> 6, c = idx & 63;
        WT[c][o] = w_in[idx] * gamma[o] * rsqrtf(var[o] + 1e-5f);
    }
    if (tid < 64) {
        float inv = gamma[tid] * rsqrtf(var[tid] + 1e-5f);
        bef[tid] = (b_in[tid] - mean[tid]) * inv + beta[tid];
    }
    for (int e = 0; e < 8; ++e) {
        int i16 = e * 256 + tid;
        int c = i16 >> 5, s = i16 & 31;
        *(float4*)&Xt[c][s * 4] = *(const float4*)(xb + ((size_t)c << 16) + hw0 + s * 4);
    }
    __syncthreads();

    int tr = tid >> 3, tc = tid & 7;
    float acc[4][8];
    #pragma unroll
    for (int p = 0; p < 4; ++p)
        #pragma unroll
        for (int q = 0; q < 8; ++q) acc[p][q] = 0.f;

    for (int c = 0; c < 64; ++c) {
        float4 a4 = *(const float4*)&Xt[c][4 * tr];
        float4 b0 = *(const float4*)&WT[c][8 * tc];
        float4 b1 = *(const float4*)&WT[c][8 * tc + 4];
        float av[4] = {a4.x, a4.y, a4.z, a4.w};
        float bv[8] = {b0.x, b0.y, b0.z, b0.w, b1.x, b1.y, b1.z, b1.w};
        #pragma unroll
        for (int p = 0; p < 4; ++p)
            #pragma unroll
            for (int q = 0; q < 8; ++q) acc[p][q] += av[p] * bv[q];
    }

    float bo[8];
    #pragma unroll
    for (int q = 0; q < 8; ++q) bo[q] = bef[8 * tc + q];
    ushort_t* xp = xbn + ((size_t)(b * 65536 + hw0 + 4 * tr) << 6) + 8 * tc;
    #pragma unroll
    for (int p = 0; p < 4; ++p) {
        union { int4 v; ushort_t s[8]; } pk;
        #pragma unroll
        for (int q = 0; q < 8; ++q) pk.s[q] = f2bf(acc[p][q] + bo[q]);
        *(int4*)(xp + (size_t)p * 64) = pk.v;
    }
}

// ---------------- Kernel 2: MFMA attention ----------------
// All operands [m][k]/[n][k] bf16 pitch 72 shorts (144B). S/OutT fp32 pitch 68.
// Split precision: wm,q,wo as hi+lo bf16 (exp path ~fp32-exact); P~,VW single bf16.
// Reassociated: out = P~ @ (V @ wo^T) / rowsum + b_out  -> no V transpose anywhere.
#define LDS_G    0        // g[64][72] bf16        -> VWT
#define LDS_V    9216     // V[64][72] bf16        -> P~
#define LDS_WMH  18432    // wmH                   -> S fp32 [64][68] -> OutT fp32
#define LDS_WML  27648    // wmL
#define LDS_QH   36864
#define LDS_QL   46080
#define LDS_WOH  55296
#define LDS_WOL  64512
#define LDS_RED  73728
#define LDS_RED2 74752
#define LDS_RS   75776
#define LDS_TOT  76032

#define MFMA(A,B,C) __builtin_amdgcn_mfma_f32_16x16x32_bf16(A, B, C, 0, 0, 0)

__device__ __forceinline__ void splitw(const float* src, short* dh, short* dl) {
    // 16 floats -> 16 bf16 hi + 16 bf16 lo, vectorized 16B IO
    union { int4 v; ushort_t s[8]; } h0, h1, l0, l1;
    float4 f0 = *(const float4*)(src);
    float4 f1 = *(const float4*)(src + 4);
    float4 f2 = *(const float4*)(src + 8);
    float4 f3 = *(const float4*)(src + 12);
    float fv[16] = {f0.x,f0.y,f0.z,f0.w, f1.x,f1.y,f1.z,f1.w,
                    f2.x,f2.y,f2.z,f2.w, f3.x,f3.y,f3.z,f3.w};
    #pragma unroll
    for (int e = 0; e < 8; ++e) {
        ushort_t h = f2bf(fv[e]);     h0.s[e] = h; l0.s[e] = f2bf(fv[e] - bf2f(h));
        ushort_t g = f2bf(fv[e + 8]); h1.s[e] = g; l1.s[e] = f2bf(fv[e + 8] - bf2f(g));
    }
    *(int4*)(dh)     = h0.v;
    *(int4*)(dh + 8) = h1.v;
    *(int4*)(dl)     = l0.v;
    *(int4*)(dl + 8) = l1.v;
}

__global__ __launch_bounds__(256, 2) void k2_attn_mfma(
    const ushort_t* __restrict__ xbn,
    const float* __restrict__ w_mask, const float* __restrict__ b_mask,
    const float* __restrict__ w_out,  const float* __restrict__ b_out,
    float* __restrict__ out)
{
    __shared__ char smem[LDS_TOT];
    short* gb   = (short*)(smem + LDS_G);
    short* vb   = (short*)(smem + LDS_V);
    short* wmh  = (short*)(smem + LDS_WMH);
    short* wml  = (short*)(smem + LDS_WML);
    short* qhb  = (short*)(smem + LDS_QH);
    short* qlb  = (short*)(smem + LDS_QL);
    short* woh  = (short*)(smem + LDS_WOH);
    short* wol  = (short*)(smem + LDS_WOL);
    float* Sb   = (float*)(smem + LDS_WMH);   // aliases wm after G1
    short* vwt  = (short*)(smem + LDS_G);     // aliases g after G1
    short* pt   = (short*)(smem + LDS_V);     // aliases V after G2
    float* outt = (float*)(smem + LDS_WMH);   // aliases S after softmax
    float* red  = (float*)(smem + LDS_RED);
    float* red2 = (float*)(smem + LDS_RED2);
    float* rsv  = (float*)(smem + LDS_RS);

    int tid = threadIdx.x;
    int wid = blockIdx.x;
    int b = wid >> 10, i = (wid >> 5) & 31, j = wid & 31;
    const ushort_t* xb = xbn + ((size_t)b << 22);

    // ---- stage g, V (raw bf16 row copies), wm split ----
    {
        int t = tid >> 2, seg = tid & 3;
        int r = t & 7, s = t >> 3;
        int pr = i * 8 + 2 * r; if (pr >= 256) pr -= 8;
        int pc = j * 8 + 2 * s; if (pc >= 256) pc -= 8;
        const ushort_t* src = xb + (((size_t)((pr << 8) | pc)) << 6) + seg * 16;
        *(int4*)(gb + t * 72 + seg * 16)     = *(const int4*)src;
        *(int4*)(gb + t * 72 + seg * 16 + 8) = *(const int4*)(src + 8);
        int vr = i * 8 + (t >> 3), vc = j * 8 + (t & 7);
        const ushort_t* vsrc = xb + (((size_t)((vr << 8) | vc)) << 6) + seg * 16;
        *(int4*)(vb + t * 72 + seg * 16)     = *(const int4*)vsrc;
        *(int4*)(vb + t * 72 + seg * 16 + 8) = *(const int4*)(vsrc + 8);
        splitw(w_mask + t * 64 + seg * 16, wmh + t * 72 + seg * 16, wml + t * 72 + seg * 16);
    }
    __syncthreads();

    int w = tid >> 6, l = tid & 63;
    int half = l >> 4, lr = l & 15;
    int mrow = (16 * w + lr) * 72;           // bf16 A/B row base for this lane's stripe
    int kc0 = half * 8, kc1 = 32 + half * 8; // k-chunk offsets

    // stage wo split (region disjoint from G1's operands; completes before sync2)
    {
        int t = tid >> 2, seg = tid & 3;
        splitw(w_out + t * 64 + seg * 16, woh + t * 72 + seg * 16, wol + t * 72 + seg * 16);
    }

    // ---- G1: q[t][o] = g @ wm^T + b_mask ; orientation A=wm(m=o), B=g(n=t) ----
    {
        short8v amh0 = *(short8v*)(wmh + mrow + kc0);
        short8v amh1 = *(short8v*)(wmh + mrow + kc1);
        short8v aml0 = *(short8v*)(wml + mrow + kc0);
        short8v aml1 = *(short8v*)(wml + mrow + kc1);
        float4 bm = *(const float4*)(b_mask + 16 * w + half * 4);
        float bmv[4] = {bm.x, bm.y, bm.z, bm.w};
        #pragma unroll
        for (int n = 0; n < 4; ++n) {
            int nrow = (16 * n + lr) * 72;
            short8v bg0 = *(short8v*)(gb + nrow + kc0);
            short8v bg1 = *(short8v*)(gb + nrow + kc1);
            f32x4 acc = {0.f, 0.f, 0.f, 0.f};
            acc = MFMA(amh0, bg0, acc);
            acc = MFMA(amh1, bg1, acc);
            acc = MFMA(aml0, bg0, acc);
            acc = MFMA(aml1, bg1, acc);
            // C: col=t=16n+lr, rows o = 16w+half*4+rr  -> pack 4 along o (b64)
            ushort_t hs[4], ls[4];
            #pragma unroll
            for (int rr = 0; rr < 4; ++rr) {
                float qv = acc[rr] + bmv[rr];
                hs[rr] = f2bf(qv);
                ls[rr] = f2bf(qv - bf2f(hs[rr]));
            }
            int qoff = (16 * n + lr) * 72 + 16 * w + half * 4;
            *(uint2*)(qhb + qoff) = make_uint2((uint_t)hs[0] | ((uint_t)hs[1] << 16),
                                               (uint_t)hs[2] | ((uint_t)hs[3] << 16));
            *(uint2*)(qlb + qoff) = make_uint2((uint_t)ls[0] | ((uint_t)ls[1] << 16),
                                               (uint_t)ls[2] | ((uint_t)ls[3] << 16));
        }
    }
    __syncthreads();

    // ---- G2: VW = V @ wo^T ; orientation A=V(m=u), B=wo(n=o) -> write VWT[o][u] ----
    {
        short8v av0 = *(short8v*)(vb + mrow + kc0);
        short8v av1 = *(short8v*)(vb + mrow + kc1);
        #pragma unroll
        for (int n = 0; n < 4; ++n) {
            int nrow = (16 * n + lr) * 72;
            short8v bh0 = *(short8v*)(woh + nrow + kc0);
            short8v bh1 = *(short8v*)(woh + nrow + kc1);
            short8v bl0 = *(short8v*)(wol + nrow + kc0);
            short8v bl1 = *(short8v*)(wol + nrow + kc1);
            f32x4 acc = {0.f, 0.f, 0.f, 0.f};
            acc = MFMA(av0, bh0, acc);
            acc = MFMA(av1, bh1, acc);
            acc = MFMA(av0, bl0, acc);
            acc = MFMA(av1, bl1, acc);
            ushort_t hs[4];
            #pragma unroll
            for (int rr = 0; rr < 4; ++rr) hs[rr] = f2bf(acc[rr]);
            int voff = (16 * n + lr) * 72 + 16 * w + half * 4;   // [o][u]
            *(uint2*)(vwt + voff) = make_uint2((uint_t)hs[0] | ((uint_t)hs[1] << 16),
                                               (uint_t)hs[2] | ((uint_t)hs[3] << 16));
        }
    }
    // ---- G3: S = q @ q^T (3-term split) ; write S[u][t] fp32 (symmetric) ----
    {
        short8v ah0 = *(short8v*)(qhb + mrow + kc0);
        short8v ah1 = *(short8v*)(qhb + mrow + kc1);
        short8v al0 = *(short8v*)(qlb + mrow + kc0);
        short8v al1 = *(short8v*)(qlb + mrow + kc1);
        #pragma unroll
        for (int n = 0; n < 4; ++n) {
            int nrow = (16 * n + lr) * 72;
            short8v bh0 = *(short8v*)(qhb + nrow + kc0);
            short8v bh1 = *(short8v*)(qhb + nrow + kc1);
            short8v bl0 = *(short8v*)(qlb + nrow + kc0);
            short8v bl1 = *(short8v*)(qlb + nrow + kc1);
            f32x4 acc = {0.f, 0.f, 0.f, 0.f};
            acc = MFMA(ah0, bh0, acc);
            acc = MFMA(ah1, bh1, acc);
            acc = MFMA(ah0, bl0, acc);
            acc = MFMA(ah1, bl1, acc);
            acc = MFMA(al0, bh0, acc);
            acc = MFMA(al1, bh1, acc);
            *(f32x4*)(Sb + (16 * n + lr) * 68 + 16 * w + half * 4) = acc;  // S[u][t]
        }
    }
    __syncthreads();

    // ---- softmax rows: P~[t][u] = exp(S[t][u]-m[t]) bf16 ; rsv[t]=1/sum ----
    {
        int row = tid >> 2, p = tid & 3;
        const float* srow = Sb + row * 68 + p * 16;
        float4 s4[4];
        #pragma unroll
        for (int q = 0; q < 4; ++q) s4[q] = *(const float4*)(srow + 4 * q);
        float m = -1e30f;
        #pragma unroll
        for (int q = 0; q < 4; ++q)
            m = fmaxf(m, fmaxf(fmaxf(s4[q].x, s4[q].y), fmaxf(s4[q].z, s4[q].w)));
        red[row * 4 + p] = m;
        __syncthreads();
        m = fmaxf(fmaxf(red[row * 4 + 0], red[row * 4 + 1]),
                  fmaxf(red[row * 4 + 2], red[row * 4 + 3]));
        union { int4 v; ushort_t s[8]; } pk0, pk1;
        float ssum = 0.f;
        #pragma unroll
        for (int q = 0; q < 4; ++q) {
            float vv[4] = {s4[q].x, s4[q].y, s4[q].z, s4[q].w};
            #pragma unroll
            for (int e = 0; e < 4; ++e) {
                ushort_t h = f2bf(__expf(vv[e] - m));
                ssum += bf2f(h);
                if (q < 2) pk0.s[q * 4 + e] = h; else pk1.s[(q - 2) * 4 + e] = h;
            }
        }
        *(int4*)(pt + row * 72 + p * 16)     = pk0.v;
        *(int4*)(pt + row * 72 + p * 16 + 8) = pk1.v;
        red2[row * 4 + p] = ssum;
        __syncthreads();
        if (p == 0)
            rsv[row] = 1.0f / (red2[row * 4] + red2[row * 4 + 1] +
                               red2[row * 4 + 2] + red2[row * 4 + 3]);
    }
    __syncthreads();

    // ---- G4: out = P~ @ VWT^T ; A=P~(m=t), B=VWT(n=o) ; epilogue /rs + b_out ----
    {
        short8v ap0 = *(short8v*)(pt + mrow + kc0);
        short8v ap1 = *(short8v*)(pt + mrow + kc1);
        float4 rv = *(const float4*)(rsv + 16 * w + half * 4);
        float rvv[4] = {rv.x, rv.y, rv.z, rv.w};
        f32x4 oacc[4];
        #pragma unroll
        for (int n = 0; n < 4; ++n) {
            int nrow = (16 * n + lr) * 72;
            short8v bv0 = *(short8v*)(vwt + nrow + kc0);
            short8v bv1 = *(short8v*)(vwt + nrow + kc1);
            f32x4 acc = {0.f, 0.f, 0.f, 0.f};
            acc = MFMA(ap0, bv0, acc);
            acc = MFMA(ap1, bv1, acc);
            oacc[n] = acc;
        }
        __syncthreads();   // S (aliased) fully read by softmax; now safe to write OutT
        #pragma unroll
        for (int n = 0; n < 4; ++n) {
            float bo = b_out[16 * n + lr];
            float4 wv = make_float4(oacc[n][0] * rvv[0] + bo, oacc[n][1] * rvv[1] + bo,
                                    oacc[n][2] * rvv[2] + bo, oacc[n][3] * rvv[3] + bo);
            *(float4*)(outt + (16 * n + lr) * 68 + 16 * w + half * 4) = wv;  // OutT[o][t]
        }
    }
    __syncthreads();

    // ---- coalesced global store ----
    {
        float* ob = out + ((size_t)b << 22);
        int base = (i * 8) * 256 + j * 8;
        for (int pp = 0; pp < 16; ++pp) {
            int e = pp * 256 + tid;
            int o = e >> 6, t = e & 63;
            ob[((size_t)o << 16) + base + ((t >> 3) << 8) + (t & 7)] = outt[o * 68 + t];
        }
    }
}

extern "C" void kernel_launch(void* const* d_in, const int* in_sizes, int n_in,
                              void* d_out, int out_size, void* d_ws, size_t ws_size,
                              hipStream_t stream) {
    const float* x      = (const float*)d_in[0];
    const float* w_in   = (const float*)d_in[1];
    const float* b_in   = (const float*)d_in[2];
    const float* gamma  = (const float*)d_in[3];
    const float* beta   = (const float*)d_in[4];
    const float* mean   = (const float*)d_in[5];
    const float* var    = (const float*)d_in[6];
    const float* w_mask = (const float*)d_in[7];
    const float* b_mask = (const float*)d_in[8];
    const float* w_out  = (const float*)d_in[9];
    const float* b_out  = (const float*)d_in[10];
    float* out = (float*)d_out;
    ushort_t* xbn = (ushort_t*)d_ws;   // 4*65536*64 bf16 = 33.5 MB

    hipLaunchKernelGGL(k1_pwbn, dim3(2048), dim3(256), 0, stream,
                       x, w_in, b_in, gamma, beta, mean, var, xbn);
    hipLaunchKernelGGL(k2_attn_mfma, dim3(4096), dim3(256), 0, stream,
                       xbn, w_mask, b_mask, w_out, b_out, out);
}

// Round 6
// 194.739 us; speedup vs baseline: 2.0105x; 1.0346x over previous
//
#include <hip/hip_runtime.h>

typedef unsigned short ushort_t;
typedef unsigned int uint_t;
typedef __attribute__((ext_vector_type(8))) short short8v;
typedef __attribute__((ext_vector_type(4))) float f32x4;

__device__ __forceinline__ float bf2f(ushort_t u) {
    union { uint_t u; float f; } v; v.u = (uint_t)u << 16; return v.f;
}
__device__ __forceinline__ ushort_t f2bf(float f) {
    union { float f; uint_t u; } v; v.f = f;
    uint_t u = v.u;
    return (ushort_t)((u + 0x7fffu + ((u >> 16) & 1u)) >> 16);  // RNE
}

#define MFMA(A,B,C) __builtin_amdgcn_mfma_f32_16x16x32_bf16(A, B, C, 0, 0, 0)

// ---------------- Kernel 1: pointwise conv + BN fold — MFMA, split precision ----------
// x: (4,64,256,256) f32 -> xbn: (4*65536, 64) bf16 channel-last.
// Per block: 64 pixels x 64 outs, K=64. x hi/lo + wef hi/lo, 3-term MFMA (~fp32 exact).
// LDS ~37 KB -> 4 blocks/CU. grid 4096.
__global__ __launch_bounds__(256, 4) void k1_pwbn_mfma(
    const float* __restrict__ x, const float* __restrict__ w_in, const float* __restrict__ b_in,
    const float* __restrict__ gamma, const float* __restrict__ beta,
    const float* __restrict__ mean, const float* __restrict__ var,
    ushort_t* __restrict__ xbn)
{
    __shared__ short xsh[64][72];   // [px][c] hi
    __shared__ short xsl[64][72];   // [px][c] lo
    __shared__ short wfh[64][72];   // [o][c] hi  (wef = w_in * gamma/sqrt(var+eps))
    __shared__ short wfl[64][72];   // [o][c] lo
    __shared__ float bef[64];

    int tid = threadIdx.x;
    int b   = blockIdx.x >> 10;              // 1024 blocks of 64 px per batch image
    int hw0 = (blockIdx.x & 1023) << 6;
    const float* xb = x + ((size_t)b << 22);

    // ---- stage x transposed (c-major global -> [px][c] LDS), hi/lo split ----
    #pragma unroll
    for (int u = 0; u < 2; ++u) {
        int idx = u * 256 + tid;             // 512 units = 32 c-pairs x 16 px-quads
        int cp = idx >> 4, pq = idx & 15;
        int c0 = cp * 2, p0 = pq * 4;
        float4 fa = *(const float4*)(xb + (size_t)c0 * 65536 + hw0 + p0);
        float4 fb = *(const float4*)(xb + (size_t)(c0 + 1) * 65536 + hw0 + p0);
        float va[4] = {fa.x, fa.y, fa.z, fa.w};
        float vb[4] = {fb.x, fb.y, fb.z, fb.w};
        #pragma unroll
        for (int e = 0; e < 4; ++e) {
            ushort_t h0 = f2bf(va[e]), h1 = f2bf(vb[e]);
            ushort_t l0 = f2bf(va[e] - bf2f(h0)), l1 = f2bf(vb[e] - bf2f(h1));
            *(uint_t*)&xsh[p0 + e][c0] = (uint_t)h0 | ((uint_t)h1 << 16);
            *(uint_t*)&xsl[p0 + e][c0] = (uint_t)l0 | ((uint_t)l1 << 16);
        }
    }
    // ---- stage wef hi/lo ([o][c] natural layout, b128 writes) ----
    #pragma unroll
    for (int v = 0; v < 2; ++v) {
        int idx = v * 256 + tid;             // 512 units = 64 o x 8 c-octs
        int o = idx >> 3, c0 = (idx & 7) * 8;
        float sc = gamma[o] * rsqrtf(var[o] + 1e-5f);
        float4 fa = *(const float4*)(w_in + o * 64 + c0);
        float4 fb = *(const float4*)(w_in + o * 64 + c0 + 4);
        float vv[8] = {fa.x, fa.y, fa.z, fa.w, fb.x, fb.y, fb.z, fb.w};
        union { int4 q; ushort_t s[8]; } ph, pl;
        #pragma unroll
        for (int e = 0; e < 8; ++e) {
            float wv = vv[e] * sc;
            ushort_t h = f2bf(wv);
            ph.s[e] = h;
            pl.s[e] = f2bf(wv - bf2f(h));
        }
        *(int4*)&wfh[o][c0] = ph.q;
        *(int4*)&wfl[o][c0] = pl.q;
    }
    if (tid < 64) {
        float inv = gamma[tid] * rsqrtf(var[tid] + 1e-5f);
        bef[tid] = (b_in[tid] - mean[tid]) * inv + beta[tid];
    }
    __syncthreads();

    // ---- MFMA: wave w owns px 16w..16w+15 (B), all 64 outs (A, 4 o-tiles) ----
    int w = tid >> 6, l = tid & 63;
    int half = l >> 4, lr = l & 15;
    int k0 = half * 8;                       // lane's k-chunk within 32-wide K step

    short8v bh[2], bl[2];
    #pragma unroll
    for (int kc = 0; kc < 2; ++kc) {
        bh[kc] = *(short8v*)&xsh[16 * w + lr][k0 + 32 * kc];
        bl[kc] = *(short8v*)&xsl[16 * w + lr][k0 + 32 * kc];
    }
    short8v ah[4][2], al[4][2];
    #pragma unroll
    for (int ot = 0; ot < 4; ++ot)
        #pragma unroll
        for (int kc = 0; kc < 2; ++kc) {
            ah[ot][kc] = *(short8v*)&wfh[16 * ot + lr][k0 + 32 * kc];
            al[ot][kc] = *(short8v*)&wfl[16 * ot + lr][k0 + 32 * kc];
        }

    ushort_t* xp = xbn + ((size_t)(b * 65536 + hw0 + 16 * w + lr) << 6);
    #pragma unroll
    for (int ot = 0; ot < 4; ++ot) {
        f32x4 acc = {0.f, 0.f, 0.f, 0.f};
        #pragma unroll
        for (int kc = 0; kc < 2; ++kc) {
            acc = MFMA(ah[ot][kc], bh[kc], acc);
            acc = MFMA(ah[ot][kc], bl[kc], acc);
            acc = MFMA(al[ot][kc], bh[kc], acc);
        }
        // D: n=px=lr (B-row), m=o = 16*ot + 4*half + reg
        int o0 = 16 * ot + 4 * half;
        float4 bq = *(const float4*)&bef[o0];
        float bqs[4] = {bq.x, bq.y, bq.z, bq.w};
        ushort_t hs[4];
        #pragma unroll
        for (int rr = 0; rr < 4; ++rr) hs[rr] = f2bf(acc[rr] + bqs[rr]);
        *(uint2*)(xp + o0) = make_uint2((uint_t)hs[0] | ((uint_t)hs[1] << 16),
                                        (uint_t)hs[2] | ((uint_t)hs[3] << 16));
    }
}

// ---------------- Kernel 2: MFMA attention (UNCHANGED from R5) ----------------
#define LDS_G    0
#define LDS_V    9216
#define LDS_WMH  18432
#define LDS_WML  27648
#define LDS_QH   36864
#define LDS_QL   46080
#define LDS_WOH  55296
#define LDS_WOL  64512
#define LDS_RED  73728
#define LDS_RED2 74752
#define LDS_RS   75776
#define LDS_TOT  76032

__device__ __forceinline__ void splitw(const float* src, short* dh, short* dl) {
    union { int4 v; ushort_t s[8]; } h0, h1, l0, l1;
    float4 f0 = *(const float4*)(src);
    float4 f1 = *(const float4*)(src + 4);
    float4 f2 = *(const float4*)(src + 8);
    float4 f3 = *(const float4*)(src + 12);
    float fv[16] = {f0.x,f0.y,f0.z,f0.w, f1.x,f1.y,f1.z,f1.w,
                    f2.x,f2.y,f2.z,f2.w, f3.x,f3.y,f3.z,f3.w};
    #pragma unroll
    for (int e = 0; e < 8; ++e) {
        ushort_t h = f2bf(fv[e]);     h0.s[e] = h; l0.s[e] = f2bf(fv[e] - bf2f(h));
        ushort_t g = f2bf(fv[e + 8]); h1.s[e] = g; l1.s[e] = f2bf(fv[e + 8] - bf2f(g));
    }
    *(int4*)(dh)     = h0.v;
    *(int4*)(dh + 8) = h1.v;
    *(int4*)(dl)     = l0.v;
    *(int4*)(dl + 8) = l1.v;
}

__global__ __launch_bounds__(256, 2) void k2_attn_mfma(
    const ushort_t* __restrict__ xbn,
    const float* __restrict__ w_mask, const float* __restrict__ b_mask,
    const float* __restrict__ w_out,  const float* __restrict__ b_out,
    float* __restrict__ out)
{
    __shared__ char smem[LDS_TOT];
    short* gb   = (short*)(smem + LDS_G);
    short* vb   = (short*)(smem + LDS_V);
    short* wmh  = (short*)(smem + LDS_WMH);
    short* wml  = (short*)(smem + LDS_WML);
    short* qhb  = (short*)(smem + LDS_QH);
    short* qlb  = (short*)(smem + LDS_QL);
    short* woh  = (short*)(smem + LDS_WOH);
    short* wol  = (short*)(smem + LDS_WOL);
    float* Sb   = (float*)(smem + LDS_WMH);
    short* vwt  = (short*)(smem + LDS_G);
    short* pt   = (short*)(smem + LDS_V);
    float* outt = (float*)(smem + LDS_WMH);
    float* red  = (float*)(smem + LDS_RED);
    float* red2 = (float*)(smem + LDS_RED2);
    float* rsv  = (float*)(smem + LDS_RS);

    int tid = threadIdx.x;
    int wid = blockIdx.x;
    int b = wid >> 10, i = (wid >> 5) & 31, j = wid & 31;
    const ushort_t* xb = xbn + ((size_t)b << 22);

    {
        int t = tid >> 2, seg = tid & 3;
        int r = t & 7, s = t >> 3;
        int pr = i * 8 + 2 * r; if (pr >= 256) pr -= 8;
        int pc = j * 8 + 2 * s; if (pc >= 256) pc -= 8;
        const ushort_t* src = xb + (((size_t)((pr << 8) | pc)) << 6) + seg * 16;
        *(int4*)(gb + t * 72 + seg * 16)     = *(const int4*)src;
        *(int4*)(gb + t * 72 + seg * 16 + 8) = *(const int4*)(src + 8);
        int vr = i * 8 + (t >> 3), vc = j * 8 + (t & 7);
        const ushort_t* vsrc = xb + (((size_t)((vr << 8) | vc)) << 6) + seg * 16;
        *(int4*)(vb + t * 72 + seg * 16)     = *(const int4*)vsrc;
        *(int4*)(vb + t * 72 + seg * 16 + 8) = *(const int4*)(vsrc + 8);
        splitw(w_mask + t * 64 + seg * 16, wmh + t * 72 + seg * 16, wml + t * 72 + seg * 16);
    }
    __syncthreads();

    int w = tid >> 6, l = tid & 63;
    int half = l >> 4, lr = l & 15;
    int mrow = (16 * w + lr) * 72;
    int kc0 = half * 8, kc1 = 32 + half * 8;

    {
        int t = tid >> 2, seg = tid & 3;
        splitw(w_out + t * 64 + seg * 16, woh + t * 72 + seg * 16, wol + t * 72 + seg * 16);
    }

    // G1: q = g @ wm^T + b_mask
    {
        short8v amh0 = *(short8v*)(wmh + mrow + kc0);
        short8v amh1 = *(short8v*)(wmh + mrow + kc1);
        short8v aml0 = *(short8v*)(wml + mrow + kc0);
        short8v aml1 = *(short8v*)(wml + mrow + kc1);
        float4 bm = *(const float4*)(b_mask + 16 * w + half * 4);
        float bmv[4] = {bm.x, bm.y, bm.z, bm.w};
        #pragma unroll
        for (int n = 0; n < 4; ++n) {
            int nrow = (16 * n + lr) * 72;
            short8v bg0 = *(short8v*)(gb + nrow + kc0);
            short8v bg1 = *(short8v*)(gb + nrow + kc1);
            f32x4 acc = {0.f, 0.f, 0.f, 0.f};
            acc = MFMA(amh0, bg0, acc);
            acc = MFMA(amh1, bg1, acc);
            acc = MFMA(aml0, bg0, acc);
            acc = MFMA(aml1, bg1, acc);
            ushort_t hs[4], ls[4];
            #pragma unroll
            for (int rr = 0; rr < 4; ++rr) {
                float qv = acc[rr] + bmv[rr];
                hs[rr] = f2bf(qv);
                ls[rr] = f2bf(qv - bf2f(hs[rr]));
            }
            int qoff = (16 * n + lr) * 72 + 16 * w + half * 4;
            *(uint2*)(qhb + qoff) = make_uint2((uint_t)hs[0] | ((uint_t)hs[1] << 16),
                                               (uint_t)hs[2] | ((uint_t)hs[3] << 16));
            *(uint2*)(qlb + qoff) = make_uint2((uint_t)ls[0] | ((uint_t)ls[1] << 16),
                                               (uint_t)ls[2] | ((uint_t)ls[3] << 16));
        }
    }
    __syncthreads();

    // G2: VWT = (V @ wo^T)^T
    {
        short8v av0 = *(short8v*)(vb + mrow + kc0);
        short8v av1 = *(short8v*)(vb + mrow + kc1);
        #pragma unroll
        for (int n = 0; n < 4; ++n) {
            int nrow = (16 * n + lr) * 72;
            short8v bh0 = *(short8v*)(woh + nrow + kc0);
            short8v bh1 = *(short8v*)(woh + nrow + kc1);
            short8v bl0 = *(short8v*)(wol + nrow + kc0);
            short8v bl1 = *(short8v*)(wol + nrow + kc1);
            f32x4 acc = {0.f, 0.f, 0.f, 0.f};
            acc = MFMA(av0, bh0, acc);
            acc = MFMA(av1, bh1, acc);
            acc = MFMA(av0, bl0, acc);
            acc = MFMA(av1, bl1, acc);
            ushort_t hs[4];
            #pragma unroll
            for (int rr = 0; rr < 4; ++rr) hs[rr] = f2bf(acc[rr]);
            int voff = (16 * n + lr) * 72 + 16 * w + half * 4;
            *(uint2*)(vwt + voff) = make_uint2((uint_t)hs[0] | ((uint_t)hs[1] << 16),
                                               (uint_t)hs[2] | ((uint_t)hs[3] << 16));
        }
    }
    // G3: S = q @ q^T (3-term)
    {
        short8v ah0 = *(short8v*)(qhb + mrow + kc0);
        short8v ah1 = *(short8v*)(qhb + mrow + kc1);
        short8v al0 = *(short8v*)(qlb + mrow + kc0);
        short8v al1 = *(short8v*)(qlb + mrow + kc1);
        #pragma unroll
        for (int n = 0; n < 4; ++n) {
            int nrow = (16 * n + lr) * 72;
            short8v bh0 = *(short8v*)(qhb + nrow + kc0);
            short8v bh1 = *(short8v*)(qhb + nrow + kc1);
            short8v bl0 = *(short8v*)(qlb + nrow + kc0);
            short8v bl1 = *(short8v*)(qlb + nrow + kc1);
            f32x4 acc = {0.f, 0.f, 0.f, 0.f};
            acc = MFMA(ah0, bh0, acc);
            acc = MFMA(ah1, bh1, acc);
            acc = MFMA(ah0, bl0, acc);
            acc = MFMA(ah1, bl1, acc);
            acc = MFMA(al0, bh0, acc);
            acc = MFMA(al1, bh1, acc);
            *(f32x4*)(Sb + (16 * n + lr) * 68 + 16 * w + half * 4) = acc;
        }
    }
    __syncthreads();

    // softmax
    {
        int row = tid >> 2, p = tid & 3;
        const float* srow = Sb + row * 68 + p * 16;
        float4 s4[4];
        #pragma unroll
        for (int q = 0; q < 4; ++q) s4[q] = *(const float4*)(srow + 4 * q);
        float m = -1e30f;
        #pragma unroll
        for (int q = 0; q < 4; ++q)
            m = fmaxf(m, fmaxf(fmaxf(s4[q].x, s4[q].y), fmaxf(s4[q].z, s4[q].w)));
        red[row * 4 + p] = m;
        __syncthreads();
        m = fmaxf(fmaxf(red[row * 4 + 0], red[row * 4 + 1]),
                  fmaxf(red[row * 4 + 2], red[row * 4 + 3]));
        union { int4 v; ushort_t s[8]; } pk0, pk1;
        float ssum = 0.f;
        #pragma unroll
        for (int q = 0; q < 4; ++q) {
            float vv[4] = {s4[q].x, s4[q].y, s4[q].z, s4[q].w};
            #pragma unroll
            for (int e = 0; e < 4; ++e) {
                ushort_t h = f2bf(__expf(vv[e] - m));
                ssum += bf2f(h);
                if (q < 2) pk0.s[q * 4 + e] = h; else pk1.s[(q - 2) * 4 + e] = h;
            }
        }
        *(int4*)(pt + row * 72 + p * 16)     = pk0.v;
        *(int4*)(pt + row * 72 + p * 16 + 8) = pk1.v;
        red2[row * 4 + p] = ssum;
        __syncthreads();
        if (p == 0)
            rsv[row] = 1.0f / (red2[row * 4] + red2[row * 4 + 1] +
                               red2[row * 4 + 2] + red2[row * 4 + 3]);
    }
    __syncthreads();

    // G4: out = P~ @ VWT^T
    {
        short8v ap0 = *(short8v*)(pt + mrow + kc0);
        short8v ap1 = *(short8v*)(pt + mrow + kc1);
        float4 rv = *(const float4*)(rsv + 16 * w + half * 4);
        float rvv[4] = {rv.x, rv.y, rv.z, rv.w};
        f32x4 oacc[4];
        #pragma unroll
        for (int n = 0; n < 4; ++n) {
            int nrow = (16 * n + lr) * 72;
            short8v bv0 = *(short8v*)(vwt + nrow + kc0);
            short8v bv1 = *(short8v*)(vwt + nrow + kc1);
            f32x4 acc = {0.f, 0.f, 0.f, 0.f};
            acc = MFMA(ap0, bv0, acc);
            acc = MFMA(ap1, bv1, acc);
            oacc[n] = acc;
        }
        __syncthreads();
        #pragma unroll
        for (int n = 0; n < 4; ++n) {
            float bo = b_out[16 * n + lr];
            float4 wv = make_float4(oacc[n][0] * rvv[0] + bo, oacc[n][1] * rvv[1] + bo,
                                    oacc[n][2] * rvv[2] + bo, oacc[n][3] * rvv[3] + bo);
            *(float4*)(outt + (16 * n + lr) * 68 + 16 * w + half * 4) = wv;
        }
    }
    __syncthreads();

    {
        float* ob = out + ((size_t)b << 22);
        int base = (i * 8) * 256 + j * 8;
        for (int pp = 0; pp < 16; ++pp) {
            int e = pp * 256 + tid;
            int o = e >> 6, t = e & 63;
            ob[((size_t)o << 16) + base + ((t >> 3) << 8) + (t & 7)] = outt[o * 68 + t];
        }
    }
}

extern "C" void kernel_launch(void* const* d_in, const int* in_sizes, int n_in,
                              void* d_out, int out_size, void* d_ws, size_t ws_size,
                              hipStream_t stream) {
    const float* x      = (const float*)d_in[0];
    const float* w_in   = (const float*)d_in[1];
    const float* b_in   = (const float*)d_in[2];
    const float* gamma  = (const float*)d_in[3];
    const float* beta   = (const float*)d_in[4];
    const float* mean   = (const float*)d_in[5];
    const float* var    = (const float*)d_in[6];
    const float* w_mask = (const float*)d_in[7];
    const float* b_mask = (const float*)d_in[8];
    const float* w_out  = (const float*)d_in[9];
    const float* b_out  = (const float*)d_in[10];
    float* out = (float*)d_out;
    ushort_t* xbn = (ushort_t*)d_ws;   // 4*65536*64 bf16 = 33.5 MB

    hipLaunchKernelGGL(k1_pwbn_mfma, dim3(4096), dim3(256), 0, stream,
                       x, w_in, b_in, gamma, beta, mean, var, xbn);
    hipLaunchKernelGGL(k2_attn_mfma, dim3(4096), dim3(256), 0, stream,
                       xbn, w_mask, b_mask, w_out, b_out, out);
}